// Round 11
// baseline (464.503 us; speedup 1.0000x reference)
//
#include <hip/hip_runtime.h>
#include <hip/hip_bf16.h>

#define HALF_ROWS 262144
#define TAU 0.04f
#define BT_OFF 1024
#define XBF_OFF (1 << 20)                    // ws+1MB: xbff 256MB (A-fragment order)
#define LIST_OFF (XBF_OFF + 268435456)

typedef __attribute__((ext_vector_type(8))) short s16x8;
typedef __attribute__((ext_vector_type(4))) float f32x4;

__device__ __forceinline__ unsigned short f2bf(float f) {
  union { float f; unsigned u; } v; v.f = f;
  unsigned r = v.u + 0x7fffu + ((v.u >> 16) & 1u);   // RTNE
  return (unsigned short)(r >> 16);
}

#define GLOAD_LDS16(g, p) \
  __builtin_amdgcn_global_load_lds((const __attribute__((address_space(1))) void*)(g), \
                                   (__attribute__((address_space(3))) void*)(p), 16, 0, 0)

__device__ __forceinline__ s16x8 cvt8(const f32x4& a, const f32x4& b) {
  union { int i[4]; s16x8 v; } u;
  asm("v_cvt_pk_bf16_f32 %0, %1, %2" : "=v"(u.i[0]) : "v"(a[0]), "v"(a[1]));
  asm("v_cvt_pk_bf16_f32 %0, %1, %2" : "=v"(u.i[1]) : "v"(a[2]), "v"(a[3]));
  asm("v_cvt_pk_bf16_f32 %0, %1, %2" : "=v"(u.i[2]) : "v"(b[0]), "v"(b[1]));
  asm("v_cvt_pk_bf16_f32 %0, %1, %2" : "=v"(u.i[3]) : "v"(b[2]), "v"(b[3]));
  return u.v;
}

// ---- prep: W1 -> Bf in MFMA B-fragment order [cb20][ksg16][lane64][8] --------
__global__ void moe_prep(const float* __restrict__ gw1, const float* __restrict__ aw1,
                         const float* __restrict__ bw1, unsigned short* __restrict__ Bf,
                         unsigned* __restrict__ cnt) {
  if (blockIdx.x == 0 && threadIdx.x == 0) *cnt = 0u;
  int idx = blockIdx.x * 512 + threadIdx.x;          // 320*512 = 163840
  int j = idx & 7, l = (idx >> 3) & 63, ks = (idx >> 9) & 15, cb = idx >> 13;
  int col = cb * 16 + (l & 15);
  int k = ks * 32 + ((l >> 4) << 3) + j;
  float v;
  if (col < 64)       v = gw1[k * 64 + col];
  else if (col < 192) v = aw1[k * 128 + (col - 64)];
  else                v = bw1[k * 128 + (col - 192)];
  Bf[idx] = f2bf(v);
}

// ---- convert: sequential NT-read x (512MB) -> xbff in A-fragment order -------
// xbff idx = ((G*16 + kc)*64 + lane)*8; lane = (row&15) + slot*16, k = kc*32+slot*8+j
__global__ __launch_bounds__(256) void moe_convert(const float* __restrict__ x,
                                                   unsigned short* __restrict__ xbff) {
  const long stride = 4096L * 256;
  const long t = (long)blockIdx.x * 256 + threadIdx.x;
#pragma unroll 1
  for (int b = 0; b < 2; ++b) {
    f32x4 v[8][2];
    const long c0 = t + (long)b * 8 * stride;
#pragma unroll
    for (int u = 0; u < 8; ++u) {
      const f32x4* p = (const f32x4*)(x + (c0 + u * stride) * 8);
      v[u][0] = __builtin_nontemporal_load(p);
      v[u][1] = __builtin_nontemporal_load(p + 1);
    }
#pragma unroll
    for (int u = 0; u < 8; ++u) {
      long cc = c0 + u * stride;
      long srow = cc >> 5;
      int k8 = (int)(cc & 31) << 3;
      long drow; int koff;
      if (srow >= HALF_ROWS) { drow = srow - HALF_ROWS; koff = 256 + k8; }
      else                   { drow = srow;             koff = k8; }
      long G = drow >> 4;
      int kc = koff >> 5, slot = (koff >> 3) & 3;
      int ln = (int)(drow & 15) + slot * 16;
      *(s16x8*)(xbff + (G << 13) + (kc << 9) + (ln << 3)) = cvt8(v[u][0], v[u][1]);
    }
  }
}

#define WAITLOHI(VLO, VHI)                                              \
  if (w < 10) asm volatile("s_waitcnt vmcnt(" #VLO ")" ::: "memory");   \
  else        asm volatile("s_waitcnt vmcnt(" #VHI ")" ::: "memory");

#define STEP(KC, CUR, NXT, DO_LOADA, DO_ISSUEB, VLO, VHI)                          \
  {                                                                                \
    if (DO_LOADA)                                                                  \
      asm volatile("global_load_dwordx4 %0, %1, off"                               \
                   : "=&v"(NXT) : "v"(ap + (((KC) + 1) << 9)));                    \
    if (DO_ISSUEB) issueB((KC) + 2);                                               \
    WAITLOHI(VLO, VHI)                                                             \
    __builtin_amdgcn_sched_barrier(0);                                             \
    __builtin_amdgcn_s_barrier();                                                  \
    __builtin_amdgcn_sched_barrier(0);                                             \
    const char* buf = Bl[(KC) & 3];                                                \
    _Pragma("unroll")                                                              \
    for (int ct = 0; ct < 20; ++ct) {                                              \
      s16x8 bfv = *(const s16x8*)(buf + (ct << 10) + (l << 4));                    \
      acc[ct] = __builtin_amdgcn_mfma_f32_16x16x32_bf16(CUR, bfv, acc[ct], 0, 0, 0);\
    }                                                                              \
  }

// ---- main: BM=256, 16 waves x (16 rows x 320 cols); A contiguous from xbff ---
__global__ __launch_bounds__(1024, 4) void moe_main(
    const unsigned short* __restrict__ xbff, const unsigned short* __restrict__ Bf,
    const float* __restrict__ gb1, const float* __restrict__ gw2, const float* __restrict__ gb2,
    const float* __restrict__ ab1, const float* __restrict__ aw2, const float* __restrict__ ab2,
    const float* __restrict__ bb1, const float* __restrict__ bw2, const float* __restrict__ bb2,
    float* __restrict__ out, unsigned* __restrict__ cnt, unsigned* __restrict__ list, int cap) {
  __shared__ char Bl[4][20480];               // 4-deep B ring (BK=32)

  const int tid = threadIdx.x;
  const int w = tid >> 6, l = tid & 63;
  const int lo = l & 15, hi = l >> 4;
  const unsigned short* ap = xbff + ((size_t)(blockIdx.x * 16 + w) << 13) + (l << 3);

  const unsigned short* bsrc = Bf + l * 8;
  auto issueB = [&](int kc) {                 // waves 0-9 fill segs 2w, 2w+1
    if (w < 10) {
      char* dst = Bl[kc & 3] + w * 2048;
      const unsigned short* g = bsrc + ((size_t)((2 * w) * 16 + kc) << 9);
      GLOAD_LDS16(g, dst);
      GLOAD_LDS16(g + 8192, dst + 1024);
    }
  };

  f32x4 acc[20];
#pragma unroll
  for (int ct = 0; ct < 20; ++ct) acc[ct] = (f32x4){0.f, 0.f, 0.f, 0.f};

  s16x8 a0, a1;
  asm volatile("global_load_dwordx4 %0, %1, off" : "=&v"(a0) : "v"(ap));
  issueB(0);
  issueB(1);

#pragma unroll 1
  for (int kc = 0; kc < 14; kc += 2) {
    STEP(kc,     a0, a1, true, true, 5, 1)
    STEP(kc + 1, a1, a0, true, true, 5, 1)
  }
  STEP(14, a0, a1, true,  false, 3, 1)
  STEP(15, a1, a0, false, false, 0, 0)

  // ---- epilogue: wave-local (16 rows x all 320 cols) --------------------------
  float pg0[4] = {0,0,0,0}, pg1[4] = {0,0,0,0};
  float pa0[4] = {0,0,0,0}, pa1[4] = {0,0,0,0};
  float pq0[4] = {0,0,0,0}, pq1[4] = {0,0,0,0};
#pragma unroll
  for (int ct = 0; ct < 20; ++ct) {
    int col = ct * 16 + lo;
    float b1, w0, w1;
    if (ct < 4)       { b1 = gb1[col];        w0 = gw2[col * 2];        w1 = gw2[col * 2 + 1]; }
    else if (ct < 12) { int c = col - 64;  b1 = ab1[c]; w0 = aw2[c * 2]; w1 = aw2[c * 2 + 1]; }
    else              { int c = col - 192; b1 = bb1[c]; w0 = bw2[c * 2]; w1 = bw2[c * 2 + 1]; }
#pragma unroll
    for (int j = 0; j < 4; ++j) {
      float h = fmaxf(acc[ct][j] + b1, 0.f);
      float t0 = h * w0, t1 = h * w1;
      if (ct < 4)       { pg0[j] += t0; pg1[j] += t1; }
      else if (ct < 12) { pa0[j] += t0; pa1[j] += t1; }
      else              { pq0[j] += t0; pq1[j] += t1; }
    }
  }
#pragma unroll
  for (int m = 1; m < 16; m <<= 1)
#pragma unroll
    for (int j = 0; j < 4; ++j) {
      pg0[j] += __shfl_xor(pg0[j], m); pg1[j] += __shfl_xor(pg1[j], m);
      pa0[j] += __shfl_xor(pa0[j], m); pa1[j] += __shfl_xor(pa1[j], m);
      pq0[j] += __shfl_xor(pq0[j], m); pq1[j] += __shfl_xor(pq1[j], m);
    }
  if (lo == 0) {
    float g2a = gb2[0], g2b = gb2[1];
    float a2a = ab2[0], a2b = ab2[1];
    float b2a = bb2[0], b2b = bb2[1];
#pragma unroll
    for (int j = 0; j < 4; ++j) {
      long grow = ((long)blockIdx.x * 256 + w * 16) + hi * 4 + j;
      float gl0 = pg0[j] + g2a, gl1 = pg1[j] + g2b;
      float fa0 = pa0[j] + a2a, fa1 = pa1[j] + a2b;
      float fb0 = pq0[j] + b2a, fb1 = pq1[j] + b2b;
      bool m0 = gl0 >= gl1;
      f32x4 o;
      o[0] = m0 ? fa0 : 0.f; o[1] = m0 ? fa1 : 0.f;
      o[2] = m0 ? 0.f : fb0; o[3] = m0 ? 0.f : fb1;
      *(f32x4*)(out + grow * 4) = o;
      float diff = gl0 - gl1;
      if (fabsf(diff) < TAU && cap > 0) {
        unsigned u = atomicAdd(cnt, 1u);
        if (u < (unsigned)cap) {
          unsigned* e = list + (size_t)u * 8;
          e[0] = (unsigned)grow;
          float* ef = (float*)(e + 4);
          ef[0] = fa0; ef[1] = fa1; ef[2] = fb0; ef[3] = fb1;
        }
      }
    }
  }
}

// ---- fixup: fp64 gate recompute for borderline rows (8 ILP chains) -----------
__global__ void moe_fixup(const float* __restrict__ x,
                          const float* __restrict__ gw1, const float* __restrict__ gb1,
                          const float* __restrict__ gw2, const float* __restrict__ gb2,
                          float* __restrict__ out, const unsigned* __restrict__ cnt,
                          const unsigned* __restrict__ list, int cap) {
  unsigned n = *cnt;
  if (n > (unsigned)cap) n = (unsigned)cap;
  const int l = threadIdx.x & 63;
  const int wid = blockIdx.x * (blockDim.x >> 6) + (threadIdx.x >> 6);
  const int nw = gridDim.x * (blockDim.x >> 6);
  for (unsigned e = wid; e < n; e += nw) {
    const unsigned* ent = list + (size_t)e * 8;
    unsigned row = ent[0];
    const float* ef = (const float*)(ent + 4);
    const float* xr0 = x + (long)row * 256;
    const float* xr1 = x + ((long)row + HALF_ROWS) * 256;
    double a[8] = {0, 0, 0, 0, 0, 0, 0, 0};
#pragma unroll 2
    for (int d = 0; d < 256; d += 8)
#pragma unroll
      for (int q = 0; q < 8; ++q)
        a[q] += (double)xr0[d + q] * (double)gw1[(d + q) * 64 + l];
#pragma unroll 2
    for (int d = 0; d < 256; d += 8)
#pragma unroll
      for (int q = 0; q < 8; ++q)
        a[q] += (double)xr1[d + q] * (double)gw1[(d + 256 + q) * 64 + l];
    double h = ((a[0] + a[1]) + (a[2] + a[3])) + ((a[4] + a[5]) + (a[6] + a[7]))
             + (double)gb1[l];
    h = h > 0.0 ? h : 0.0;
    double t0 = h * (double)gw2[l * 2];
    double t1 = h * (double)gw2[l * 2 + 1];
#pragma unroll
    for (int m = 1; m < 64; m <<= 1) {
      t0 += __shfl_xor(t0, m);
      t1 += __shfl_xor(t1, m);
    }
    if (l == 0) {
      bool m0 = (t0 + (double)gb2[0]) >= (t1 + (double)gb2[1]);
      f32x4 o;
      o[0] = m0 ? ef[0] : 0.f; o[1] = m0 ? ef[1] : 0.f;
      o[2] = m0 ? 0.f : ef[2]; o[3] = m0 ? 0.f : ef[3];
      *(f32x4*)(out + (size_t)row * 4) = o;
    }
  }
}

extern "C" void kernel_launch(void* const* d_in, const int* in_sizes, int n_in,
                              void* d_out, int out_size, void* d_ws, size_t ws_size,
                              hipStream_t stream) {
  const float* x   = (const float*)d_in[0];
  const float* gw1 = (const float*)d_in[1];
  const float* gb1 = (const float*)d_in[2];
  const float* gw2 = (const float*)d_in[3];
  const float* gb2 = (const float*)d_in[4];
  const float* aw1 = (const float*)d_in[5];
  const float* ab1 = (const float*)d_in[6];
  const float* aw2 = (const float*)d_in[7];
  const float* ab2 = (const float*)d_in[8];
  const float* bw1 = (const float*)d_in[9];
  const float* bb1 = (const float*)d_in[10];
  const float* bw2 = (const float*)d_in[11];
  const float* bb2 = (const float*)d_in[12];
  float* out = (float*)d_out;

  unsigned char* ws = (unsigned char*)d_ws;
  unsigned* cnt = (unsigned*)ws;
  unsigned short* Bf = (unsigned short*)(ws + BT_OFF);
  unsigned short* xbff = (unsigned short*)(ws + XBF_OFF);
  unsigned* list = (unsigned*)(ws + LIST_OFF);
  long cap_l = ((long)ws_size - (long)LIST_OFF) / 32;
  int cap = cap_l < 0 ? 0 : (cap_l > 262144 ? 262144 : (int)cap_l);

  moe_prep<<<320, 512, 0, stream>>>(gw1, aw1, bw1, Bf, cnt);
  moe_convert<<<4096, 256, 0, stream>>>(x, xbff);
  moe_main<<<1024, 1024, 0, stream>>>(xbff, Bf, gb1, gw2, gb2, ab1, aw2, ab2,
                                      bb1, bw2, bb2, out, cnt, list, cap);
  moe_fixup<<<2048, 256, 0, stream>>>(x, gw1, gb1, gw2, gb2, out, cnt, list, cap);
}

// Round 12
// 294.336 us; speedup vs baseline: 1.5781x; 1.5781x over previous
//
#include <hip/hip_runtime.h>
#include <hip/hip_bf16.h>

#define HALF_ROWS 262144
#define TAU 0.04f
#define BT_OFF 1024
#define LIST_OFF (BT_OFF + 320 * 512 * 2)   // 1024 + 327680

typedef __attribute__((ext_vector_type(8))) short s16x8;
typedef __attribute__((ext_vector_type(4))) float f32x4;

__device__ __forceinline__ unsigned short f2bf(float f) {
  union { float f; unsigned u; } v; v.f = f;
  unsigned r = v.u + 0x7fffu + ((v.u >> 16) & 1u);   // RTNE
  return (unsigned short)(r >> 16);
}

#define GLOAD_LDS16(g, p) \
  __builtin_amdgcn_global_load_lds((const __attribute__((address_space(1))) void*)(g), \
                                   (__attribute__((address_space(3))) void*)(p), 16, 0, 0)

__device__ __forceinline__ s16x8 cvt8(const f32x4& a, const f32x4& b) {
  union { int i[4]; s16x8 v; } u;
  asm("v_cvt_pk_bf16_f32 %0, %1, %2" : "=v"(u.i[0]) : "v"(a[0]), "v"(a[1]));
  asm("v_cvt_pk_bf16_f32 %0, %1, %2" : "=v"(u.i[1]) : "v"(a[2]), "v"(a[3]));
  asm("v_cvt_pk_bf16_f32 %0, %1, %2" : "=v"(u.i[2]) : "v"(b[0]), "v"(b[1]));
  asm("v_cvt_pk_bf16_f32 %0, %1, %2" : "=v"(u.i[3]) : "v"(b[2]), "v"(b[3]));
  return u.v;
}

// ---- prep: W1 -> Bf in MFMA B-fragment order [cb20][ks16][lane64][8] ---------
__global__ void moe_prep(const float* __restrict__ gw1, const float* __restrict__ aw1,
                         const float* __restrict__ bw1, unsigned short* __restrict__ Bf,
                         unsigned* __restrict__ cnt) {
  if (blockIdx.x == 0 && threadIdx.x == 0) *cnt = 0u;
  int idx = blockIdx.x * 512 + threadIdx.x;          // 320*512 = 163840
  int j = idx & 7, l = (idx >> 3) & 63, ks = (idx >> 9) & 15, cb = idx >> 13;
  int col = cb * 16 + (l & 15);
  int k = ks * 32 + ((l >> 4) << 3) + j;
  float v;
  if (col < 64)       v = gw1[k * 64 + col];
  else if (col < 192) v = aw1[k * 128 + (col - 64)];
  else                v = bw1[k * 128 + (col - 192)];
  Bf[idx] = f2bf(v);
}

// per-wave DMA count: waves 0-3 do 3 segs, waves 4-7 do 2
#define WAITB(V3, V2)                                                  \
  if (w < 4) asm volatile("s_waitcnt vmcnt(" #V3 ")" ::: "memory");    \
  else       asm volatile("s_waitcnt vmcnt(" #V2 ")" ::: "memory");

// one K-chunk: prefetch A(KC+1)+B(KC+2), counted wait, barrier, cvt, 40 MFMA
#define STEP(KC, C0A, C0B, C1A, C1B, N0A, N0B, N1A, N1B, DO_A, DO_B, V3, V2)       \
  {                                                                                \
    if (DO_A) {                                                                    \
      const int kn = (KC) + 1;                                                     \
      const float* pb = (kn < 8) ? apA : apA2;                                     \
      const float* p0 = pb + (kn & 7) * 32;                                        \
      const float* p1 = p0 + 16 * 256;                                             \
      asm volatile("global_load_dwordx4 %0, %1, off" : "=&v"(N0A) : "v"(p0));      \
      asm volatile("global_load_dwordx4 %0, %1, off" : "=&v"(N0B) : "v"(p0 + 4));  \
      asm volatile("global_load_dwordx4 %0, %1, off" : "=&v"(N1A) : "v"(p1));      \
      asm volatile("global_load_dwordx4 %0, %1, off" : "=&v"(N1B) : "v"(p1 + 4));  \
    }                                                                              \
    if (DO_B) issueB((KC) + 2);                                                    \
    WAITB(V3, V2)                                                                  \
    __builtin_amdgcn_sched_barrier(0);                                             \
    __builtin_amdgcn_s_barrier();                                                  \
    __builtin_amdgcn_sched_barrier(0);                                             \
    s16x8 af0 = cvt8(C0A, C0B);                                                    \
    s16x8 af1 = cvt8(C1A, C1B);                                                    \
    const char* buf = Bl[(KC) & 3];                                                \
    _Pragma("unroll")                                                              \
    for (int ct = 0; ct < 20; ++ct) {                                              \
      s16x8 bfv = *(const s16x8*)(buf + (ct << 10) + (l << 4));                    \
      acc0[ct] = __builtin_amdgcn_mfma_f32_16x16x32_bf16(af0, bfv, acc0[ct], 0, 0, 0); \
      acc1[ct] = __builtin_amdgcn_mfma_f32_16x16x32_bf16(af1, bfv, acc1[ct], 0, 0, 0); \
    }                                                                              \
  }

// ---- main: BM=256, 8 waves x (32 rows x 320 cols); x lines touched once ------
// A: per-lane 32B gather = one whole 128B line per row per chunk, sequential in
// kc (16 m13-like streams/wave). B: 4-deep LDS ring, counted vmcnt, 1 barrier.
__global__ __launch_bounds__(512, 2) void moe_main(
    const float* __restrict__ x, const unsigned short* __restrict__ Bf,
    const float* __restrict__ gb1, const float* __restrict__ gw2, const float* __restrict__ gb2,
    const float* __restrict__ ab1, const float* __restrict__ aw2, const float* __restrict__ ab2,
    const float* __restrict__ bb1, const float* __restrict__ bw2, const float* __restrict__ bb2,
    float* __restrict__ out, unsigned* __restrict__ cnt, unsigned* __restrict__ list, int cap) {
  __shared__ char Bl[4][20480];               // 4-deep B ring (BK=32)

  const int tid = threadIdx.x;
  const int w = tid >> 6, l = tid & 63;
  const int lo = l & 15, hi = l >> 4;
  const long r0 = (long)blockIdx.x * 256 + w * 32;
  const float* apA  = x + (r0 + lo) * 256 + hi * 8;          // frag rows r0..+15
  const float* apA2 = apA + (long)HALF_ROWS * 256;           // second batch half

  const unsigned short* bsrc = Bf + l * 8;
  const int s0 = (w < 4) ? w * 3 : 12 + (w - 4) * 2;
  const int ns = (w < 4) ? 3 : 2;
  auto issueB = [&](int kc) {
    char* dst = Bl[kc & 3] + s0 * 1024;
    const unsigned short* g = bsrc + ((size_t)(s0 * 16 + kc) << 9);
#pragma unroll
    for (int s = 0; s < 3; ++s)
      if (s < ns) GLOAD_LDS16(g + ((size_t)s << 13), dst + s * 1024);
  };

  f32x4 acc0[20], acc1[20];
#pragma unroll
  for (int ct = 0; ct < 20; ++ct) {
    acc0[ct] = (f32x4){0.f, 0.f, 0.f, 0.f};
    acc1[ct] = (f32x4){0.f, 0.f, 0.f, 0.f};
  }

  f32x4 xA0, xA1, xA2, xA3, xB0, xB1, xB2, xB3;
  // prologue: A(0) via asm (4 loads), B(0), B(1)
  asm volatile("global_load_dwordx4 %0, %1, off" : "=&v"(xA0) : "v"(apA));
  asm volatile("global_load_dwordx4 %0, %1, off" : "=&v"(xA1) : "v"(apA + 4));
  asm volatile("global_load_dwordx4 %0, %1, off" : "=&v"(xA2) : "v"(apA + 16 * 256));
  asm volatile("global_load_dwordx4 %0, %1, off" : "=&v"(xA3) : "v"(apA + 16 * 256 + 4));
  issueB(0);
  issueB(1);

#pragma unroll 1
  for (int kc = 0; kc < 14; kc += 2) {
    STEP(kc,     xA0, xA1, xA2, xA3, xB0, xB1, xB2, xB3, true, true, 10, 8)
    STEP(kc + 1, xB0, xB1, xB2, xB3, xA0, xA1, xA2, xA3, true, true, 10, 8)
  }
  STEP(14, xA0, xA1, xA2, xA3, xB0, xB1, xB2, xB3, true,  false, 7, 6)
  STEP(15, xB0, xB1, xB2, xB3, xA0, xA1, xA2, xA3, false, false, 0, 0)

  // ---- epilogue: wave-local; two 16-row groups ------------------------------
  float b1v, w0v, w1v;
#define EPI(ACC, RT)                                                              \
  {                                                                               \
    float pg0[4] = {0,0,0,0}, pg1[4] = {0,0,0,0};                                 \
    float pa0[4] = {0,0,0,0}, pa1[4] = {0,0,0,0};                                 \
    float pq0[4] = {0,0,0,0}, pq1[4] = {0,0,0,0};                                 \
    _Pragma("unroll")                                                             \
    for (int ct = 0; ct < 20; ++ct) {                                             \
      int col = ct * 16 + lo;                                                     \
      if (ct < 4)       { b1v = gb1[col];        w0v = gw2[col * 2];        w1v = gw2[col * 2 + 1]; } \
      else if (ct < 12) { int c = col - 64;  b1v = ab1[c]; w0v = aw2[c * 2]; w1v = aw2[c * 2 + 1]; } \
      else              { int c = col - 192; b1v = bb1[c]; w0v = bw2[c * 2]; w1v = bw2[c * 2 + 1]; } \
      _Pragma("unroll")                                                           \
      for (int j = 0; j < 4; ++j) {                                               \
        float h = fmaxf(ACC[ct][j] + b1v, 0.f);                                   \
        float t0 = h * w0v, t1 = h * w1v;                                         \
        if (ct < 4)       { pg0[j] += t0; pg1[j] += t1; }                         \
        else if (ct < 12) { pa0[j] += t0; pa1[j] += t1; }                         \
        else              { pq0[j] += t0; pq1[j] += t1; }                         \
      }                                                                           \
    }                                                                             \
    _Pragma("unroll")                                                             \
    for (int m = 1; m < 16; m <<= 1)                                              \
      _Pragma("unroll")                                                           \
      for (int j = 0; j < 4; ++j) {                                               \
        pg0[j] += __shfl_xor(pg0[j], m); pg1[j] += __shfl_xor(pg1[j], m);         \
        pa0[j] += __shfl_xor(pa0[j], m); pa1[j] += __shfl_xor(pa1[j], m);         \
        pq0[j] += __shfl_xor(pq0[j], m); pq1[j] += __shfl_xor(pq1[j], m);         \
      }                                                                           \
    if (lo == 0) {                                                                \
      _Pragma("unroll")                                                           \
      for (int j = 0; j < 4; ++j) {                                               \
        long grow = r0 + (RT) * 16 + hi * 4 + j;                                  \
        float gl0 = pg0[j] + gb2[0], gl1 = pg1[j] + gb2[1];                       \
        float fa0 = pa0[j] + ab2[0], fa1 = pa1[j] + ab2[1];                       \
        float fb0 = pq0[j] + bb2[0], fb1 = pq1[j] + bb2[1];                       \
        bool m0 = gl0 >= gl1;                                                     \
        f32x4 o;                                                                  \
        o[0] = m0 ? fa0 : 0.f; o[1] = m0 ? fa1 : 0.f;                             \
        o[2] = m0 ? 0.f : fb0; o[3] = m0 ? 0.f : fb1;                             \
        *(f32x4*)(out + grow * 4) = o;                                            \
        float diff = gl0 - gl1;                                                   \
        if (fabsf(diff) < TAU && cap > 0) {                                       \
          unsigned u = atomicAdd(cnt, 1u);                                        \
          if (u < (unsigned)cap) {                                                \
            unsigned* e = list + (size_t)u * 8;                                   \
            e[0] = (unsigned)grow;                                                \
            float* ef = (float*)(e + 4);                                          \
            ef[0] = fa0; ef[1] = fa1; ef[2] = fb0; ef[3] = fb1;                   \
          }                                                                       \
        }                                                                         \
      }                                                                           \
    }                                                                             \
  }
  EPI(acc0, 0)
  EPI(acc1, 1)
}

// ---- fixup: fp64 gate recompute for borderline rows (8 ILP chains) -----------
__global__ void moe_fixup(const float* __restrict__ x,
                          const float* __restrict__ gw1, const float* __restrict__ gb1,
                          const float* __restrict__ gw2, const float* __restrict__ gb2,
                          float* __restrict__ out, const unsigned* __restrict__ cnt,
                          const unsigned* __restrict__ list, int cap) {
  unsigned n = *cnt;
  if (n > (unsigned)cap) n = (unsigned)cap;
  const int l = threadIdx.x & 63;
  const int wid = blockIdx.x * (blockDim.x >> 6) + (threadIdx.x >> 6);
  const int nw = gridDim.x * (blockDim.x >> 6);
  for (unsigned e = wid; e < n; e += nw) {
    const unsigned* ent = list + (size_t)e * 8;
    unsigned row = ent[0];
    const float* ef = (const float*)(ent + 4);
    const float* xr0 = x + (long)row * 256;
    const float* xr1 = x + ((long)row + HALF_ROWS) * 256;
    double a[8] = {0, 0, 0, 0, 0, 0, 0, 0};
#pragma unroll 2
    for (int d = 0; d < 256; d += 8)
#pragma unroll
      for (int q = 0; q < 8; ++q)
        a[q] += (double)xr0[d + q] * (double)gw1[(d + q) * 64 + l];
#pragma unroll 2
    for (int d = 0; d < 256; d += 8)
#pragma unroll
      for (int q = 0; q < 8; ++q)
        a[q] += (double)xr1[d + q] * (double)gw1[(d + 256 + q) * 64 + l];
    double h = ((a[0] + a[1]) + (a[2] + a[3])) + ((a[4] + a[5]) + (a[6] + a[7]))
             + (double)gb1[l];
    h = h > 0.0 ? h : 0.0;
    double t0 = h * (double)gw2[l * 2];
    double t1 = h * (double)gw2[l * 2 + 1];
#pragma unroll
    for (int m = 1; m < 64; m <<= 1) {
      t0 += __shfl_xor(t0, m);
      t1 += __shfl_xor(t1, m);
    }
    if (l == 0) {
      bool m0 = (t0 + (double)gb2[0]) >= (t1 + (double)gb2[1]);
      f32x4 o;
      o[0] = m0 ? ef[0] : 0.f; o[1] = m0 ? ef[1] : 0.f;
      o[2] = m0 ? 0.f : ef[2]; o[3] = m0 ? 0.f : ef[3];
      *(f32x4*)(out + (size_t)row * 4) = o;
    }
  }
}

extern "C" void kernel_launch(void* const* d_in, const int* in_sizes, int n_in,
                              void* d_out, int out_size, void* d_ws, size_t ws_size,
                              hipStream_t stream) {
  const float* x   = (const float*)d_in[0];
  const float* gw1 = (const float*)d_in[1];
  const float* gb1 = (const float*)d_in[2];
  const float* gw2 = (const float*)d_in[3];
  const float* gb2 = (const float*)d_in[4];
  const float* aw1 = (const float*)d_in[5];
  const float* ab1 = (const float*)d_in[6];
  const float* aw2 = (const float*)d_in[7];
  const float* ab2 = (const float*)d_in[8];
  const float* bw1 = (const float*)d_in[9];
  const float* bb1 = (const float*)d_in[10];
  const float* bw2 = (const float*)d_in[11];
  const float* bb2 = (const float*)d_in[12];
  float* out = (float*)d_out;

  unsigned char* ws = (unsigned char*)d_ws;
  unsigned* cnt = (unsigned*)ws;
  unsigned short* Bf = (unsigned short*)(ws + BT_OFF);
  unsigned* list = (unsigned*)(ws + LIST_OFF);
  long cap_l = ((long)ws_size - (long)LIST_OFF) / 32;
  int cap = cap_l < 0 ? 0 : (cap_l > 262144 ? 262144 : (int)cap_l);

  moe_prep<<<320, 512, 0, stream>>>(gw1, aw1, bw1, Bf, cnt);
  moe_main<<<1024, 512, 0, stream>>>(x, Bf, gb1, gw2, gb2, ab1, aw2, ab2,
                                     bb1, bw2, bb2, out, cnt, list, cap);
  moe_fixup<<<2048, 256, 0, stream>>>(x, gw1, gb1, gw2, gb2, out, cnt, list, cap);
}

// Round 13
// 285.165 us; speedup vs baseline: 1.6289x; 1.0322x over previous
//
#include <hip/hip_runtime.h>
#include <hip/hip_bf16.h>

#define HALF_ROWS 262144
#define TAU 0.04f
#define BT_OFF 1024
#define LIST_OFF (BT_OFF + 320 * 512 * 2)   // 1024 + 327680
#define NC 16

typedef __attribute__((ext_vector_type(8))) short s16x8;
typedef __attribute__((ext_vector_type(4))) float f32x4;

__device__ __forceinline__ unsigned short f2bf(float f) {
  union { float f; unsigned u; } v; v.f = f;
  unsigned r = v.u + 0x7fffu + ((v.u >> 16) & 1u);   // RTNE
  return (unsigned short)(r >> 16);
}

#define GLOAD_LDS16(g, p) \
  __builtin_amdgcn_global_load_lds((const __attribute__((address_space(1))) void*)(g), \
                                   (__attribute__((address_space(3))) void*)(p), 16, 0, 0)

__device__ __forceinline__ s16x8 cvt8(const f32x4& a, const f32x4& b) {
  union { int i[4]; s16x8 v; } u;
  asm("v_cvt_pk_bf16_f32 %0, %1, %2" : "=v"(u.i[0]) : "v"(a[0]), "v"(a[1]));
  asm("v_cvt_pk_bf16_f32 %0, %1, %2" : "=v"(u.i[1]) : "v"(a[2]), "v"(a[3]));
  asm("v_cvt_pk_bf16_f32 %0, %1, %2" : "=v"(u.i[2]) : "v"(b[0]), "v"(b[1]));
  asm("v_cvt_pk_bf16_f32 %0, %1, %2" : "=v"(u.i[3]) : "v"(b[2]), "v"(b[3]));
  return u.v;
}

// ---- prep: W1 -> Bf in MFMA B-fragment order [cb20][ks16][lane64][8] ---------
__global__ void moe_prep(const float* __restrict__ gw1, const float* __restrict__ aw1,
                         const float* __restrict__ bw1, unsigned short* __restrict__ Bf,
                         unsigned* __restrict__ cnt) {
  if (blockIdx.x == 0 && threadIdx.x == 0) *cnt = 0u;
  int idx = blockIdx.x * 512 + threadIdx.x;          // 320*512 = 163840
  int j = idx & 7, l = (idx >> 3) & 63, ks = (idx >> 9) & 15, cb = idx >> 13;
  int col = cb * 16 + (l & 15);
  int k = ks * 32 + ((l >> 4) << 3) + j;
  float v;
  if (col < 64)       v = gw1[k * 64 + col];
  else if (col < 192) v = aw1[k * 128 + (col - 64)];
  else                v = bw1[k * 128 + (col - 192)];
  Bf[idx] = f2bf(v);
}

// ---- main: producer/consumer wave specialization -----------------------------
// 12 waves: w0-3 = producers (ALL memory: A reg-staged 2-deep, B DMA 3-ring,
// steady vmcnt(9), never drain to 0 till tail). w4-11 = consumers (16 rows
// each, LDS->MFMA only). One barrier per chunk. BM=128, BK=32, 16 chunks.
__global__ __launch_bounds__(768, 3) void moe_main(
    const float* __restrict__ x, const unsigned short* __restrict__ Bf,
    const float* __restrict__ gb1, const float* __restrict__ gw2, const float* __restrict__ gb2,
    const float* __restrict__ ab1, const float* __restrict__ aw2, const float* __restrict__ ab2,
    const float* __restrict__ bb1, const float* __restrict__ bw2, const float* __restrict__ bb2,
    float* __restrict__ out, unsigned* __restrict__ cnt, unsigned* __restrict__ list, int cap) {
  __shared__ char Asl[2][8192];               // A ring: [grp8][lane64][16B]
  __shared__ char Bsl[3][20480];              // B ring: [cb20][lane64][16B]

  const int tid = threadIdx.x;
  const int w = tid >> 6, l = tid & 63;
  const int lo = l & 15, hi = l >> 4;
  const long br = (long)blockIdx.x * 128;

  if (w < 4) {
    // ======================= PRODUCER =======================
    const float* apg0 = x + (br + w * 32 + lo) * 256 + hi * 8;   // group w*2
    const unsigned short* bsrc = Bf + l * 8;
    const int cb0 = w * 5;

    f32x4 sA[4], sB[4];
#define ISSUE_A(KC, S)                                                             \
    {                                                                              \
      const float* pb = ((KC) < 8) ? apg0 : (apg0 + (long)HALF_ROWS * 256);        \
      const float* p0 = pb + ((KC) & 7) * 32;                                      \
      const float* p1 = p0 + 16 * 256;                                             \
      asm volatile("global_load_dwordx4 %0, %1, off" : "=&v"(S[0]) : "v"(p0));     \
      asm volatile("global_load_dwordx4 %0, %1, off" : "=&v"(S[1]) : "v"(p0 + 4)); \
      asm volatile("global_load_dwordx4 %0, %1, off" : "=&v"(S[2]) : "v"(p1));     \
      asm volatile("global_load_dwordx4 %0, %1, off" : "=&v"(S[3]) : "v"(p1 + 4)); \
    }
    auto issueB = [&](int kc) {
      char* dst = Bsl[((unsigned)kc) % 3u] + cb0 * 1024;
#pragma unroll
      for (int s = 0; s < 5; ++s)
        GLOAD_LDS16(bsrc + (((size_t)((cb0 + s) * 16 + kc)) << 9), dst + s * 1024);
    };
#define COMMIT_A(KC, S)                                                            \
    {                                                                              \
      char* dst = Asl[(KC) & 1];                                                   \
      s16x8 v0 = cvt8(S[0], S[1]);                                                 \
      s16x8 v1 = cvt8(S[2], S[3]);                                                 \
      *(s16x8*)(dst + (w * 2) * 1024 + l * 16) = v0;                               \
      *(s16x8*)(dst + (w * 2 + 1) * 1024 + l * 16) = v1;                           \
    }
#define PWAIT(N) asm volatile("s_waitcnt vmcnt(" #N ")" ::: "memory"); \
                 __builtin_amdgcn_sched_barrier(0)
#define PBAR()   asm volatile("s_waitcnt lgkmcnt(0)" ::: "memory");    \
                 __builtin_amdgcn_s_barrier()

    ISSUE_A(0, sA) issueB(0);
    ISSUE_A(1, sB) issueB(1);
    PWAIT(9);                         // A0+B0 landed (A1+B1 remain)
    COMMIT_A(0, sA)
    PBAR();                           // barrier #1: chunk0 ready

#pragma unroll 1
    for (int kc = 0; kc < 14; kc += 2) {
      // step: commit kc+1 (sB), issue kc+2 (sA)
      ISSUE_A(kc + 2, sA) issueB(kc + 2);
      PWAIT(9);
      COMMIT_A(kc + 1, sB)
      PBAR();
      // step: commit kc+2 (sA), issue kc+3 (sB)
      if (kc + 3 < NC) {
        ISSUE_A(kc + 3, sB) issueB(kc + 3);
        PWAIT(9);
      } else {
        PWAIT(0);
      }
      COMMIT_A(kc + 2, sA)
      PBAR();
    }
    PWAIT(0);
    COMMIT_A(15, sB)
    PBAR();                           // barrier #16: chunk15 ready
    // producer done (16 barriers total)
  } else {
    // ======================= CONSUMER =======================
    const int cw = w - 4;             // 0..7, owns rows br + cw*16 ..+15
    f32x4 acc[20];
#pragma unroll
    for (int ct = 0; ct < 20; ++ct) acc[ct] = (f32x4){0.f, 0.f, 0.f, 0.f};

#pragma unroll 1
    for (int kc = 0; kc < NC; ++kc) {
      __builtin_amdgcn_s_barrier();   // barrier #kc+1: chunk kc ready
      asm volatile("" ::: "memory");
      const char* ab = Asl[kc & 1];
      const char* bb = Bsl[((unsigned)kc) % 3u];
      s16x8 af = *(const s16x8*)(ab + cw * 1024 + l * 16);
#pragma unroll
      for (int ct = 0; ct < 20; ++ct) {
        s16x8 bf = *(const s16x8*)(bb + ct * 1024 + l * 16);
        acc[ct] = __builtin_amdgcn_mfma_f32_16x16x32_bf16(af, bf, acc[ct], 0, 0, 0);
      }
    }
    // (16 barriers total — matches producers)

    // ---- epilogue: wave-local, 16 rows x all 320 cols ----
    float pg0[4] = {0,0,0,0}, pg1[4] = {0,0,0,0};
    float pa0[4] = {0,0,0,0}, pa1[4] = {0,0,0,0};
    float pq0[4] = {0,0,0,0}, pq1[4] = {0,0,0,0};
#pragma unroll
    for (int ct = 0; ct < 20; ++ct) {
      int col = ct * 16 + lo;
      float b1, w0, w1;
      if (ct < 4)       { b1 = gb1[col];        w0 = gw2[col * 2];        w1 = gw2[col * 2 + 1]; }
      else if (ct < 12) { int c = col - 64;  b1 = ab1[c]; w0 = aw2[c * 2]; w1 = aw2[c * 2 + 1]; }
      else              { int c = col - 192; b1 = bb1[c]; w0 = bw2[c * 2]; w1 = bw2[c * 2 + 1]; }
#pragma unroll
      for (int j = 0; j < 4; ++j) {
        float h = fmaxf(acc[ct][j] + b1, 0.f);
        float t0 = h * w0, t1 = h * w1;
        if (ct < 4)       { pg0[j] += t0; pg1[j] += t1; }
        else if (ct < 12) { pa0[j] += t0; pa1[j] += t1; }
        else              { pq0[j] += t0; pq1[j] += t1; }
      }
    }
#pragma unroll
    for (int m = 1; m < 16; m <<= 1)
#pragma unroll
      for (int j = 0; j < 4; ++j) {
        pg0[j] += __shfl_xor(pg0[j], m); pg1[j] += __shfl_xor(pg1[j], m);
        pa0[j] += __shfl_xor(pa0[j], m); pa1[j] += __shfl_xor(pa1[j], m);
        pq0[j] += __shfl_xor(pq0[j], m); pq1[j] += __shfl_xor(pq1[j], m);
      }
    if (lo == 0) {
#pragma unroll
      for (int j = 0; j < 4; ++j) {
        long grow = br + cw * 16 + hi * 4 + j;
        float gl0 = pg0[j] + gb2[0], gl1 = pg1[j] + gb2[1];
        float fa0 = pa0[j] + ab2[0], fa1 = pa1[j] + ab2[1];
        float fb0 = pq0[j] + bb2[0], fb1 = pq1[j] + bb2[1];
        bool m0 = gl0 >= gl1;
        f32x4 o;
        o[0] = m0 ? fa0 : 0.f; o[1] = m0 ? fa1 : 0.f;
        o[2] = m0 ? 0.f : fb0; o[3] = m0 ? 0.f : fb1;
        *(f32x4*)(out + grow * 4) = o;
        float diff = gl0 - gl1;
        if (fabsf(diff) < TAU && cap > 0) {
          unsigned u = atomicAdd(cnt, 1u);
          if (u < (unsigned)cap) {
            unsigned* e = list + (size_t)u * 8;
            e[0] = (unsigned)grow;
            float* ef = (float*)(e + 4);
            ef[0] = fa0; ef[1] = fa1; ef[2] = fb0; ef[3] = fb1;
          }
        }
      }
    }
  }
}

// ---- fixup: fp64 gate recompute for borderline rows (8 ILP chains) -----------
__global__ void moe_fixup(const float* __restrict__ x,
                          const float* __restrict__ gw1, const float* __restrict__ gb1,
                          const float* __restrict__ gw2, const float* __restrict__ gb2,
                          float* __restrict__ out, const unsigned* __restrict__ cnt,
                          const unsigned* __restrict__ list, int cap) {
  unsigned n = *cnt;
  if (n > (unsigned)cap) n = (unsigned)cap;
  const int l = threadIdx.x & 63;
  const int wid = blockIdx.x * (blockDim.x >> 6) + (threadIdx.x >> 6);
  const int nw = gridDim.x * (blockDim.x >> 6);
  for (unsigned e = wid; e < n; e += nw) {
    const unsigned* ent = list + (size_t)e * 8;
    unsigned row = ent[0];
    const float* ef = (const float*)(ent + 4);
    const float* xr0 = x + (long)row * 256;
    const float* xr1 = x + ((long)row + HALF_ROWS) * 256;
    double a[8] = {0, 0, 0, 0, 0, 0, 0, 0};
#pragma unroll 2
    for (int d = 0; d < 256; d += 8)
#pragma unroll
      for (int q = 0; q < 8; ++q)
        a[q] += (double)xr0[d + q] * (double)gw1[(d + q) * 64 + l];
#pragma unroll 2
    for (int d = 0; d < 256; d += 8)
#pragma unroll
      for (int q = 0; q < 8; ++q)
        a[q] += (double)xr1[d + q] * (double)gw1[(d + 256 + q) * 64 + l];
    double h = ((a[0] + a[1]) + (a[2] + a[3])) + ((a[4] + a[5]) + (a[6] + a[7]))
             + (double)gb1[l];
    h = h > 0.0 ? h : 0.0;
    double t0 = h * (double)gw2[l * 2];
    double t1 = h * (double)gw2[l * 2 + 1];
#pragma unroll
    for (int m = 1; m < 64; m <<= 1) {
      t0 += __shfl_xor(t0, m);
      t1 += __shfl_xor(t1, m);
    }
    if (l == 0) {
      bool m0 = (t0 + (double)gb2[0]) >= (t1 + (double)gb2[1]);
      f32x4 o;
      o[0] = m0 ? ef[0] : 0.f; o[1] = m0 ? ef[1] : 0.f;
      o[2] = m0 ? 0.f : ef[2]; o[3] = m0 ? 0.f : ef[3];
      *(f32x4*)(out + (size_t)row * 4) = o;
    }
  }
}

extern "C" void kernel_launch(void* const* d_in, const int* in_sizes, int n_in,
                              void* d_out, int out_size, void* d_ws, size_t ws_size,
                              hipStream_t stream) {
  const float* x   = (const float*)d_in[0];
  const float* gw1 = (const float*)d_in[1];
  const float* gb1 = (const float*)d_in[2];
  const float* gw2 = (const float*)d_in[3];
  const float* gb2 = (const float*)d_in[4];
  const float* aw1 = (const float*)d_in[5];
  const float* ab1 = (const float*)d_in[6];
  const float* aw2 = (const float*)d_in[7];
  const float* ab2 = (const float*)d_in[8];
  const float* bw1 = (const float*)d_in[9];
  const float* bb1 = (const float*)d_in[10];
  const float* bw2 = (const float*)d_in[11];
  const float* bb2 = (const float*)d_in[12];
  float* out = (float*)d_out;

  unsigned char* ws = (unsigned char*)d_ws;
  unsigned* cnt = (unsigned*)ws;
  unsigned short* Bf = (unsigned short*)(ws + BT_OFF);
  unsigned* list = (unsigned*)(ws + LIST_OFF);
  long cap_l = ((long)ws_size - (long)LIST_OFF) / 32;
  int cap = cap_l < 0 ? 0 : (cap_l > 262144 ? 262144 : (int)cap_l);

  moe_prep<<<320, 512, 0, stream>>>(gw1, aw1, bw1, Bf, cnt);
  moe_main<<<2048, 768, 0, stream>>>(x, Bf, gb1, gw2, gb2, ab1, aw2, ab2,
                                     bb1, bw2, bb2, out, cnt, list, cap);
  moe_fixup<<<2048, 256, 0, stream>>>(x, gw1, gb1, gw2, gb2, out, cnt, list, cap);
}